// Round 3
// baseline (413.476 us; speedup 1.0000x reference)
//
#include <hip/hip_runtime.h>

// ---------------------------------------------------------------------------
// SelfAttention: x[2,512,64,64] f32 -> qkv(1x1conv) -> 8-head attn (n=4096,d=64)
// -> proj -> out [2,512,4096] f32.
// Pipeline: prep_weights, prep_transpose, qkv_gemm (mixed-orientation),
// flash_attn (online softmax, LDS P round-trip), proj_gemm.
// All matmuls: mfma_f32_16x16x32_bf16; f32 accum.
// R1 fix: staging covered only half of each LDS tile (256 thr x 8 shorts vs
// 4096 needed) -> uninitialized LDS fed MFMA (absmax 0.318 / NaN). Now each
// thread stages 16 shorts (2x s16x8).
// R2: broker timeout, never ran on HW — resubmitting unchanged.
// ---------------------------------------------------------------------------

typedef __attribute__((ext_vector_type(8))) short s16x8;   // 8 bf16 (4 VGPR) frag / memory
typedef __attribute__((ext_vector_type(4))) float f32x4;   // mfma C/D
typedef __attribute__((ext_vector_type(4))) unsigned short u16x4;

__device__ __forceinline__ unsigned short f2bf(float f) {
  unsigned u = __builtin_bit_cast(unsigned, f);
  u += 0x7fffu + ((u >> 16) & 1u);           // round-to-nearest-even
  return (unsigned short)(u >> 16);
}

// ---- kernel 0a: convert qkv_w (1536x512) and proj_w (512x512) f32->bf16 ----
__global__ __launch_bounds__(256) void prep_weights(
    const float* __restrict__ qkv_w, const float* __restrict__ proj_w,
    short* __restrict__ wq, short* __restrict__ wp) {
  int t = blockIdx.x * 256 + threadIdx.x;     // 262144 threads, 4 elems each
  const int NQ = 1536 * 512 / 4;              // 196608 float4's in qkv_w
  if (t < NQ) {
    float4 v = ((const float4*)qkv_w)[t];
    u16x4 o; o[0] = f2bf(v.x); o[1] = f2bf(v.y); o[2] = f2bf(v.z); o[3] = f2bf(v.w);
    ((u16x4*)wq)[t] = o;
  } else {
    int t2 = t - NQ;                          // < 65536
    float4 v = ((const float4*)proj_w)[t2];
    u16x4 o; o[0] = f2bf(v.x); o[1] = f2bf(v.y); o[2] = f2bf(v.z); o[3] = f2bf(v.w);
    ((u16x4*)wp)[t2] = o;
  }
}

// ---- kernel 0b: x [b][c=512][n=4096] f32 -> Xt [b][n][c] bf16 (c contiguous) ----
__global__ __launch_bounds__(256) void prep_transpose(
    const float* __restrict__ x, short* __restrict__ xt) {
  __shared__ short TL[64 * 72];               // [n][c] tile, pad 72
  const int b = blockIdx.z, c0 = blockIdx.y * 64, n0 = blockIdx.x * 64;
  const int t = threadIdx.x;
  const int cr = t >> 4, n4 = (t & 15) * 4;
#pragma unroll
  for (int i = 0; i < 4; i++) {
    int c = cr + i * 16;
    float4 v = *(const float4*)(x + ((size_t)(b * 512 + c0 + c)) * 4096 + n0 + n4);
    TL[(n4 + 0) * 72 + c] = (short)f2bf(v.x);
    TL[(n4 + 1) * 72 + c] = (short)f2bf(v.y);
    TL[(n4 + 2) * 72 + c] = (short)f2bf(v.z);
    TL[(n4 + 3) * 72 + c] = (short)f2bf(v.w);
  }
  __syncthreads();
  const int n = t >> 2;
#pragma unroll
  for (int s2 = 0; s2 < 2; s2++) {
    int s = (t & 3) * 2 + s2;
    s16x8 v = *(const s16x8*)&TL[n * 72 + s * 8];
    *(s16x8*)(xt + ((size_t)(b * 4096 + n0 + n)) * 512 + c0 + s * 8) = v;
  }
}

// ---- kernel 1: qkv GEMM. W[1536x512] x X^T -> Q,K (swapped orientation, [n][o])
//      and V (natural, [o][n]). 128x128 tile, BK=32, 4 waves (2x2), 16 mfma/step.
__global__ __launch_bounds__(256) void qkv_gemm(
    const short* __restrict__ wq, const short* __restrict__ xt,
    const float* __restrict__ qkv_b,
    short* __restrict__ qkbuf,   // [b][n][1024]  (Q cols 0..511, K cols 512..1023)
    short* __restrict__ vbuf) {  // [b][512][4096]  V as [h*64+d][n]
  __shared__ short Al[128 * 40];  // W rows [o][c], pad 40
  __shared__ short Bl[128 * 40];  // X rows [n][c], pad 40
  const int b = blockIdx.z;
  const int m0 = blockIdx.y * 128, n0 = blockIdx.x * 128;
  const bool swapped = (blockIdx.y < 8);      // Q,K region: emit D^T = [n][o]
  const int t = threadIdx.x, lane = t & 63, wid = t >> 6;
  const int wr = wid >> 1, wc = wid & 1;
  const int srow = t >> 1, scol = (t & 1) * 16;   // 16 shorts per thread per tile
  const short* gA = wq + (size_t)(m0 + srow) * 512 + scol;
  const short* gB = xt + ((size_t)(b * 4096 + n0 + srow)) * 512 + scol;
  short* lA = &Al[srow * 40 + scol];
  short* lB = &Bl[srow * 40 + scol];
  const short* As = swapped ? Bl : Al;        // A-frag source rows (D rows)
  const short* Bs = swapped ? Al : Bl;        // B-frag source rows (D cols)
  f32x4 acc[4][4] = {};
  for (int ks = 0; ks < 16; ks++) {
    *(s16x8*)lA       = *(const s16x8*)(gA + ks * 32);
    *(s16x8*)(lA + 8) = *(const s16x8*)(gA + ks * 32 + 8);
    *(s16x8*)lB       = *(const s16x8*)(gB + ks * 32);
    *(s16x8*)(lB + 8) = *(const s16x8*)(gB + ks * 32 + 8);
    __syncthreads();
    s16x8 af[4], bf[4];
#pragma unroll
    for (int i = 0; i < 4; i++) {
      af[i] = *(const s16x8*)&As[(wr * 64 + i * 16 + (lane & 15)) * 40 + ((lane >> 4) << 3)];
      bf[i] = *(const s16x8*)&Bs[(wc * 64 + i * 16 + (lane & 15)) * 40 + ((lane >> 4) << 3)];
    }
#pragma unroll
    for (int i = 0; i < 4; i++)
#pragma unroll
      for (int j = 0; j < 4; j++)
        acc[i][j] = __builtin_amdgcn_mfma_f32_16x16x32_bf16(af[i], bf[j], acc[i][j], 0, 0, 0);
    __syncthreads();
  }
  if (!swapped) {                             // V region: D[o][n] -> vbuf
#pragma unroll
    for (int i = 0; i < 4; i++)
#pragma unroll
      for (int r = 0; r < 4; r++) {
        int orow = m0 + wr * 64 + i * 16 + ((lane >> 4) << 2) + r;
        float bias = qkv_b[orow];
#pragma unroll
        for (int j = 0; j < 4; j++) {
          int ncol = n0 + wc * 64 + j * 16 + (lane & 15);
          vbuf[((size_t)(b * 512 + orow - 1024)) * 4096 + ncol] = (short)f2bf(acc[i][j][r] + bias);
        }
      }
  } else {                                    // Q/K region: D[n][o] -> qkbuf
#pragma unroll
    for (int j = 0; j < 4; j++) {
      int ocol = m0 + wc * 64 + j * 16 + (lane & 15);
      float bias = qkv_b[ocol];
#pragma unroll
      for (int i = 0; i < 4; i++)
#pragma unroll
        for (int r = 0; r < 4; r++) {
          int nrow = n0 + wr * 64 + i * 16 + ((lane >> 4) << 2) + r;
          qkbuf[((size_t)(b * 4096 + nrow)) * 1024 + ocol] = (short)f2bf(acc[i][j][r] + bias);
        }
    }
  }
}

// ---- kernel 2: flash attention. Per block: one (b,h), 128 q-rows, 4 waves x 32 q.
//      KV tiles of 64. Q in regs; K,V in padded LDS; P via per-wave LDS round-trip.
__global__ __launch_bounds__(256) void flash_attn(
    const short* __restrict__ qkbuf, const short* __restrict__ vbuf,
    short* __restrict__ aout) {                // [b][n][512] bf16
  __shared__ short Kl[64 * 72];                // [kpos][d]
  __shared__ short Vl[64 * 72];                // [d][kpos]
  __shared__ short Pl[4 * 32 * 72];            // per-wave [q][kpos]
  const int t = threadIdx.x, lane = t & 63, wid = t >> 6;
  const int bh = blockIdx.y, b = bh >> 3, h = bh & 7;
  const int qbase = blockIdx.x * 128 + wid * 32;
  const float SL = 0.125f * 1.44269504088896f;  // scale * log2(e)

  s16x8 qf[2][2];
#pragma unroll
  for (int mi = 0; mi < 2; mi++)
#pragma unroll
    for (int kd = 0; kd < 2; kd++) {
      int qrow = qbase + mi * 16 + (lane & 15);
      int doff = kd * 32 + ((lane >> 4) << 3);
      qf[mi][kd] = *(const s16x8*)(qkbuf + ((size_t)(b * 4096 + qrow)) * 1024 + h * 64 + doff);
    }
  f32x4 oacc[2][4] = {};
  float mrow[2][4], lrow[2][4];
#pragma unroll
  for (int mi = 0; mi < 2; mi++)
#pragma unroll
    for (int r = 0; r < 4; r++) { mrow[mi][r] = -__builtin_inff(); lrow[mi][r] = 0.f; }

  const int srow = t >> 2, sseg = (t & 3) * 16;   // 16 shorts per thread per tile
  const short* gK = qkbuf + ((size_t)(b * 4096 + srow)) * 1024 + 512 + h * 64 + sseg;
  const short* gV = vbuf + ((size_t)(b * 512 + h * 64 + srow)) * 4096 + sseg;
  short* lK = &Kl[srow * 72 + sseg];
  short* lV = &Vl[srow * 72 + sseg];
  short* myP = &Pl[wid * 32 * 72];

  for (int kt = 0; kt < 64; kt++) {
    const int kp0 = kt * 64;
    *(s16x8*)lK       = *(const s16x8*)(gK + (size_t)kp0 * 1024);
    *(s16x8*)(lK + 8) = *(const s16x8*)(gK + (size_t)kp0 * 1024 + 8);
    *(s16x8*)lV       = *(const s16x8*)(gV + kp0);
    *(s16x8*)(lV + 8) = *(const s16x8*)(gV + kp0 + 8);
    __syncthreads();
    // ---- S = Q K^T (scaled later) ----
    s16x8 kf[4][2];
#pragma unroll
    for (int ni = 0; ni < 4; ni++)
#pragma unroll
      for (int kd = 0; kd < 2; kd++)
        kf[ni][kd] = *(const s16x8*)&Kl[(ni * 16 + (lane & 15)) * 72 + kd * 32 + ((lane >> 4) << 3)];
    f32x4 s[2][4] = {};
#pragma unroll
    for (int mi = 0; mi < 2; mi++)
#pragma unroll
      for (int ni = 0; ni < 4; ni++) {
        s[mi][ni] = __builtin_amdgcn_mfma_f32_16x16x32_bf16(qf[mi][0], kf[ni][0], s[mi][ni], 0, 0, 0);
        s[mi][ni] = __builtin_amdgcn_mfma_f32_16x16x32_bf16(qf[mi][1], kf[ni][1], s[mi][ni], 0, 0, 0);
      }
    // ---- online softmax (rows spread over 16 lanes; reduce via shfl_xor) ----
#pragma unroll
    for (int mi = 0; mi < 2; mi++)
#pragma unroll
      for (int r = 0; r < 4; r++) {
        float t0 = fmaxf(fmaxf(s[mi][0][r], s[mi][1][r]), fmaxf(s[mi][2][r], s[mi][3][r])) * SL;
#pragma unroll
        for (int m2 = 1; m2 < 16; m2 <<= 1) t0 = fmaxf(t0, __shfl_xor(t0, m2));
        float mn = fmaxf(mrow[mi][r], t0);
        float alpha = exp2f(mrow[mi][r] - mn);   // first tile: exp2(-inf)=0
        mrow[mi][r] = mn;
        float ps = 0.f;
#pragma unroll
        for (int ni = 0; ni < 4; ni++) {
          float p = exp2f(s[mi][ni][r] * SL - mn);
          s[mi][ni][r] = p;
          ps += p;
        }
#pragma unroll
        for (int m2 = 1; m2 < 16; m2 <<= 1) ps += __shfl_xor(ps, m2);
        lrow[mi][r] = lrow[mi][r] * alpha + ps;
#pragma unroll
        for (int di = 0; di < 4; di++) oacc[mi][di][r] *= alpha;
        int prow = (mi * 16 + ((lane >> 4) << 2) + r) * 72;
#pragma unroll
        for (int ni = 0; ni < 4; ni++)
          myP[prow + ni * 16 + (lane & 15)] = (short)f2bf(s[mi][ni][r]);
      }
    __syncthreads();   // P visibility (also orders before restage)
    // ---- O += P V ----
#pragma unroll
    for (int kd = 0; kd < 2; kd++) {
      s16x8 pa[2], vbf[4];
#pragma unroll
      for (int mi = 0; mi < 2; mi++)
        pa[mi] = *(const s16x8*)&myP[(mi * 16 + (lane & 15)) * 72 + kd * 32 + ((lane >> 4) << 3)];
#pragma unroll
      for (int di = 0; di < 4; di++)
        vbf[di] = *(const s16x8*)&Vl[(di * 16 + (lane & 15)) * 72 + kd * 32 + ((lane >> 4) << 3)];
#pragma unroll
      for (int mi = 0; mi < 2; mi++)
#pragma unroll
        for (int di = 0; di < 4; di++)
          oacc[mi][di] = __builtin_amdgcn_mfma_f32_16x16x32_bf16(pa[mi], vbf[di], oacc[mi][di], 0, 0, 0);
    }
    __syncthreads();   // protect Kl/Vl before next stage
  }
  // ---- epilogue: O/l -> aout [b][q][h*64+d] ----
#pragma unroll
  for (int mi = 0; mi < 2; mi++)
#pragma unroll
    for (int r = 0; r < 4; r++) {
      float inv = 1.f / lrow[mi][r];
      int qrow = qbase + mi * 16 + ((lane >> 4) << 2) + r;
#pragma unroll
      for (int di = 0; di < 4; di++) {
        int dc = di * 16 + (lane & 15);
        aout[((size_t)(b * 4096 + qrow)) * 512 + h * 64 + dc] = (short)f2bf(oacc[mi][di][r] * inv);
      }
    }
}

// ---- kernel 3: proj GEMM. W[512x512] x AOut^T -> out [b][512][4096] f32 + bias ----
__global__ __launch_bounds__(256) void proj_gemm(
    const short* __restrict__ wp, const short* __restrict__ aout,
    const float* __restrict__ proj_b, float* __restrict__ out) {
  __shared__ short Al[128 * 40];
  __shared__ short Bl[128 * 40];
  const int b = blockIdx.z;
  const int m0 = blockIdx.y * 128, n0 = blockIdx.x * 128;
  const int t = threadIdx.x, lane = t & 63, wid = t >> 6;
  const int wr = wid >> 1, wc = wid & 1;
  const int srow = t >> 1, scol = (t & 1) * 16;
  const short* gA = wp + (size_t)(m0 + srow) * 512 + scol;
  const short* gB = aout + ((size_t)(b * 4096 + n0 + srow)) * 512 + scol;
  short* lA = &Al[srow * 40 + scol];
  short* lB = &Bl[srow * 40 + scol];
  f32x4 acc[4][4] = {};
  for (int ks = 0; ks < 16; ks++) {
    *(s16x8*)lA       = *(const s16x8*)(gA + ks * 32);
    *(s16x8*)(lA + 8) = *(const s16x8*)(gA + ks * 32 + 8);
    *(s16x8*)lB       = *(const s16x8*)(gB + ks * 32);
    *(s16x8*)(lB + 8) = *(const s16x8*)(gB + ks * 32 + 8);
    __syncthreads();
    s16x8 af[4], bf[4];
#pragma unroll
    for (int i = 0; i < 4; i++) {
      af[i] = *(const s16x8*)&Al[(wr * 64 + i * 16 + (lane & 15)) * 40 + ((lane >> 4) << 3)];
      bf[i] = *(const s16x8*)&Bl[(wc * 64 + i * 16 + (lane & 15)) * 40 + ((lane >> 4) << 3)];
    }
#pragma unroll
    for (int i = 0; i < 4; i++)
#pragma unroll
      for (int j = 0; j < 4; j++)
        acc[i][j] = __builtin_amdgcn_mfma_f32_16x16x32_bf16(af[i], bf[j], acc[i][j], 0, 0, 0);
    __syncthreads();
  }
#pragma unroll
  for (int i = 0; i < 4; i++)
#pragma unroll
    for (int r = 0; r < 4; r++) {
      int orow = m0 + wr * 64 + i * 16 + ((lane >> 4) << 2) + r;
      float bias = proj_b[orow];
#pragma unroll
      for (int j = 0; j < 4; j++) {
        int ncol = n0 + wc * 64 + j * 16 + (lane & 15);
        out[((size_t)(b * 512 + orow)) * 4096 + ncol] = acc[i][j][r] + bias;
      }
    }
}

extern "C" void kernel_launch(void* const* d_in, const int* in_sizes, int n_in,
                              void* d_out, int out_size, void* d_ws, size_t ws_size,
                              hipStream_t stream) {
  const float* x      = (const float*)d_in[0];  // [2,512,64,64]
  const float* qkv_w  = (const float*)d_in[1];  // [1536,512]
  const float* qkv_b  = (const float*)d_in[2];  // [1536]
  const float* proj_w = (const float*)d_in[3];  // [512,512]
  const float* proj_b = (const float*)d_in[4];  // [512]
  float* out = (float*)d_out;                   // [2,512,4096]
  char* ws = (char*)d_ws;
  // ws layout (bytes): wq 1.5M | wp 0.5M | xt 8M | qk 16M | v 8M | ao 8M = 42 MiB
  short* wq = (short*)(ws);
  short* wp = (short*)(ws + 1572864);
  short* xt = (short*)(ws + 2097152);
  short* qk = (short*)(ws + 10485760);
  short* vb = (short*)(ws + 27262976);
  short* ao = (short*)(ws + 35651584);

  prep_weights  <<<1024, 256, 0, stream>>>(qkv_w, proj_w, wq, wp);
  prep_transpose<<<dim3(64, 8, 2), 256, 0, stream>>>(x, xt);
  qkv_gemm      <<<dim3(32, 12, 2), 256, 0, stream>>>(wq, xt, qkv_b, qk, vb);
  flash_attn    <<<dim3(32, 16), 256, 0, stream>>>(qk, vb, ao);
  proj_gemm     <<<dim3(32, 4, 2), 256, 0, stream>>>(wp, ao, proj_b, out);
}

// Round 4
// 288.645 us; speedup vs baseline: 1.4325x; 1.4325x over previous
//
#include <hip/hip_runtime.h>

// ---------------------------------------------------------------------------
// SelfAttention: x[2,512,64,64] f32 -> qkv(1x1conv) -> 8-head attn (n=4096,d=64)
// -> proj -> out [2,512,4096] f32.
// R3 passed (413us; flash 322us, MfmaUtil 8.6%, VALU 46%).
// R4: flash rewrite — swapped QK^T (S^T: q=lane&15 -> in-register softmax,
// max=15 fmax+2 shfl, sum deferred), P via cvt_pk_bf16 + ds_write_b64,
// 2 barriers/tile (P is per-wave), async K/V preload (T14-lite),
// Q pre-scaled by 0.125*log2e at qkv_gemm.
// ---------------------------------------------------------------------------

typedef __attribute__((ext_vector_type(8))) short s16x8;   // 8 bf16 (4 VGPR)
typedef __attribute__((ext_vector_type(4))) float f32x4;   // mfma C/D
typedef __attribute__((ext_vector_type(4))) unsigned short u16x4;

__device__ __forceinline__ unsigned short f2bf(float f) {
  unsigned u = __builtin_bit_cast(unsigned, f);
  u += 0x7fffu + ((u >> 16) & 1u);           // round-to-nearest-even
  return (unsigned short)(u >> 16);
}

__device__ __forceinline__ unsigned cvt_pk_bf16(float lo, float hi) {
  unsigned r;
  asm("v_cvt_pk_bf16_f32 %0, %1, %2" : "=v"(r) : "v"(lo), "v"(hi));
  return r;  // low16 = bf16(lo), high16 = bf16(hi)
}

// ---- kernel 0a: convert qkv_w (1536x512) and proj_w (512x512) f32->bf16 ----
__global__ __launch_bounds__(256) void prep_weights(
    const float* __restrict__ qkv_w, const float* __restrict__ proj_w,
    short* __restrict__ wq, short* __restrict__ wp) {
  int t = blockIdx.x * 256 + threadIdx.x;
  const int NQ = 1536 * 512 / 4;
  if (t < NQ) {
    float4 v = ((const float4*)qkv_w)[t];
    u16x4 o; o[0] = f2bf(v.x); o[1] = f2bf(v.y); o[2] = f2bf(v.z); o[3] = f2bf(v.w);
    ((u16x4*)wq)[t] = o;
  } else {
    int t2 = t - NQ;
    float4 v = ((const float4*)proj_w)[t2];
    u16x4 o; o[0] = f2bf(v.x); o[1] = f2bf(v.y); o[2] = f2bf(v.z); o[3] = f2bf(v.w);
    ((u16x4*)wp)[t2] = o;
  }
}

// ---- kernel 0b: x [b][c=512][n=4096] f32 -> Xt [b][n][c] bf16 ----
__global__ __launch_bounds__(256) void prep_transpose(
    const float* __restrict__ x, short* __restrict__ xt) {
  __shared__ short TL[64 * 72];
  const int b = blockIdx.z, c0 = blockIdx.y * 64, n0 = blockIdx.x * 64;
  const int t = threadIdx.x;
  const int cr = t >> 4, n4 = (t & 15) * 4;
#pragma unroll
  for (int i = 0; i < 4; i++) {
    int c = cr + i * 16;
    float4 v = *(const float4*)(x + ((size_t)(b * 512 + c0 + c)) * 4096 + n0 + n4);
    TL[(n4 + 0) * 72 + c] = (short)f2bf(v.x);
    TL[(n4 + 1) * 72 + c] = (short)f2bf(v.y);
    TL[(n4 + 2) * 72 + c] = (short)f2bf(v.z);
    TL[(n4 + 3) * 72 + c] = (short)f2bf(v.w);
  }
  __syncthreads();
  const int n = t >> 2;
#pragma unroll
  for (int s2 = 0; s2 < 2; s2++) {
    int s = (t & 3) * 2 + s2;
    s16x8 v = *(const s16x8*)&TL[n * 72 + s * 8];
    *(s16x8*)(xt + ((size_t)(b * 4096 + n0 + n)) * 512 + c0 + s * 8) = v;
  }
}

// ---- kernel 1: qkv GEMM. Q,K emitted [n][o] (swapped), V [o][n] (natural).
//      Q additionally pre-scaled by 0.125*log2(e) for the flash exp2 path.
__global__ __launch_bounds__(256) void qkv_gemm(
    const short* __restrict__ wq, const short* __restrict__ xt,
    const float* __restrict__ qkv_b,
    short* __restrict__ qkbuf,   // [b][n][1024]  (Q cols 0..511 scaled, K 512..1023)
    short* __restrict__ vbuf) {  // [b][512][4096]
  __shared__ short Al[128 * 40];
  __shared__ short Bl[128 * 40];
  const int b = blockIdx.z;
  const int m0 = blockIdx.y * 128, n0 = blockIdx.x * 128;
  const bool swapped = (blockIdx.y < 8);
  const int t = threadIdx.x, lane = t & 63, wid = t >> 6;
  const int wr = wid >> 1, wc = wid & 1;
  const int srow = t >> 1, scol = (t & 1) * 16;
  const short* gA = wq + (size_t)(m0 + srow) * 512 + scol;
  const short* gB = xt + ((size_t)(b * 4096 + n0 + srow)) * 512 + scol;
  short* lA = &Al[srow * 40 + scol];
  short* lB = &Bl[srow * 40 + scol];
  const short* As = swapped ? Bl : Al;
  const short* Bs = swapped ? Al : Bl;
  f32x4 acc[4][4] = {};
  for (int ks = 0; ks < 16; ks++) {
    *(s16x8*)lA       = *(const s16x8*)(gA + ks * 32);
    *(s16x8*)(lA + 8) = *(const s16x8*)(gA + ks * 32 + 8);
    *(s16x8*)lB       = *(const s16x8*)(gB + ks * 32);
    *(s16x8*)(lB + 8) = *(const s16x8*)(gB + ks * 32 + 8);
    __syncthreads();
    s16x8 af[4], bf[4];
#pragma unroll
    for (int i = 0; i < 4; i++) {
      af[i] = *(const s16x8*)&As[(wr * 64 + i * 16 + (lane & 15)) * 40 + ((lane >> 4) << 3)];
      bf[i] = *(const s16x8*)&Bs[(wc * 64 + i * 16 + (lane & 15)) * 40 + ((lane >> 4) << 3)];
    }
#pragma unroll
    for (int i = 0; i < 4; i++)
#pragma unroll
      for (int j = 0; j < 4; j++)
        acc[i][j] = __builtin_amdgcn_mfma_f32_16x16x32_bf16(af[i], bf[j], acc[i][j], 0, 0, 0);
    __syncthreads();
  }
  if (!swapped) {                             // V region
#pragma unroll
    for (int i = 0; i < 4; i++)
#pragma unroll
      for (int r = 0; r < 4; r++) {
        int orow = m0 + wr * 64 + i * 16 + ((lane >> 4) << 2) + r;
        float bias = qkv_b[orow];
#pragma unroll
        for (int j = 0; j < 4; j++) {
          int ncol = n0 + wc * 64 + j * 16 + (lane & 15);
          vbuf[((size_t)(b * 512 + orow - 1024)) * 4096 + ncol] = (short)f2bf(acc[i][j][r] + bias);
        }
      }
  } else {                                    // Q/K region: D^T -> [n][o]
    const float qs = (m0 < 512) ? 0.18033688f : 1.0f;   // 0.125 * log2(e) for Q
#pragma unroll
    for (int j = 0; j < 4; j++) {
      int ocol = m0 + wc * 64 + j * 16 + (lane & 15);
      float bias = qkv_b[ocol];
#pragma unroll
      for (int i = 0; i < 4; i++)
#pragma unroll
        for (int r = 0; r < 4; r++) {
          int nrow = n0 + wr * 64 + i * 16 + ((lane >> 4) << 2) + r;
          qkbuf[((size_t)(b * 4096 + nrow)) * 1024 + ocol] = (short)f2bf((acc[i][j][r] + bias) * qs);
        }
    }
  }
}

// ---- kernel 2: flash attention, swapped-QK^T in-register softmax ----
// Block: one (b,h), 128 q-rows, 4 waves x 32 q. KV tiles of 64.
// S^T = mfma(K,Q): lane holds S[q=mi*16+(lane&15)][k=ni*16+g*4+r].
// Softmax: 15 fmax + 2 shfl (max), sum deferred per-lane. P -> LDS as b64
// of cvt_pk pairs; PV unswapped (alpha redistributed via 4 shfl/mi).
__global__ __launch_bounds__(256) void flash_attn(
    const short* __restrict__ qkbuf, const short* __restrict__ vbuf,
    short* __restrict__ aout) {                // [b][n][512] bf16
  __shared__ short Kl[64 * 72];                // [kpos][d]
  __shared__ short Vl[64 * 72];                // [d][kpos]
  __shared__ short Pl[4 * 32 * 72];            // per-wave [q][kpos]
  const int t = threadIdx.x, lane = t & 63, wid = t >> 6;
  const int g = lane >> 4, c = lane & 15;
  const int bh = blockIdx.y, b = bh >> 3, h = bh & 7;
  const int qbase = blockIdx.x * 128 + wid * 32;

  s16x8 qf[2][2];                              // Q pre-scaled by 0.125*log2e
#pragma unroll
  for (int mi = 0; mi < 2; mi++)
#pragma unroll
    for (int kd = 0; kd < 2; kd++)
      qf[mi][kd] = *(const s16x8*)(qkbuf + ((size_t)(b * 4096 + qbase + mi * 16 + c)) * 1024
                                   + h * 64 + kd * 32 + g * 8);

  f32x4 oacc[2][4] = {};                       // O[q=g*4+r (per mi)][d=di*16+c]
  float mrow[2] = {-__builtin_inff(), -__builtin_inff()};
  float lrow[2] = {0.f, 0.f};                  // per-lane partial (16 k each)

  const int srow = t >> 2, sseg = (t & 3) * 16;
  const short* gK = qkbuf + ((size_t)(b * 4096 + srow)) * 1024 + 512 + h * 64 + sseg;
  const short* gV = vbuf + ((size_t)(b * 512 + h * 64 + srow)) * 4096 + sseg;
  short* lK = &Kl[srow * 72 + sseg];
  short* lV = &Vl[srow * 72 + sseg];
  short* myP = &Pl[wid * 32 * 72];

  // preload tile 0 (T14-lite: global->reg early, reg->LDS at loop head)
  s16x8 rK0 = *(const s16x8*)gK,       rK1 = *(const s16x8*)(gK + 8);
  s16x8 rV0 = *(const s16x8*)gV,       rV1 = *(const s16x8*)(gV + 8);

  for (int kt = 0; kt < 64; kt++) {
    *(s16x8*)lK = rK0;  *(s16x8*)(lK + 8) = rK1;
    *(s16x8*)lV = rV0;  *(s16x8*)(lV + 8) = rV1;
    __syncthreads();
    if (kt < 63) {                             // issue next tile under compute
      const short* nK = gK + (size_t)(kt + 1) * 64 * 1024;
      const short* nV = gV + (kt + 1) * 64;
      rK0 = *(const s16x8*)nK;  rK1 = *(const s16x8*)(nK + 8);
      rV0 = *(const s16x8*)nV;  rV1 = *(const s16x8*)(nV + 8);
    }
    // ---- S^T = K Q^T ----
    s16x8 kf[4][2];
#pragma unroll
    for (int ni = 0; ni < 4; ni++)
#pragma unroll
      for (int kd = 0; kd < 2; kd++)
        kf[ni][kd] = *(const s16x8*)&Kl[(ni * 16 + c) * 72 + kd * 32 + g * 8];
    f32x4 st[4][2] = {};
#pragma unroll
    for (int ni = 0; ni < 4; ni++)
#pragma unroll
      for (int mi = 0; mi < 2; mi++) {
        st[ni][mi] = __builtin_amdgcn_mfma_f32_16x16x32_bf16(kf[ni][0], qf[mi][0], st[ni][mi], 0, 0, 0);
        st[ni][mi] = __builtin_amdgcn_mfma_f32_16x16x32_bf16(kf[ni][1], qf[mi][1], st[ni][mi], 0, 0, 0);
      }
    // ---- softmax (in-register; one q per lane per mi) ----
#pragma unroll
    for (int mi = 0; mi < 2; mi++) {
      float t01 = fmaxf(fmaxf(st[0][mi][0], st[0][mi][1]), fmaxf(st[0][mi][2], st[0][mi][3]));
      float t23 = fmaxf(fmaxf(st[1][mi][0], st[1][mi][1]), fmaxf(st[1][mi][2], st[1][mi][3]));
      float t45 = fmaxf(fmaxf(st[2][mi][0], st[2][mi][1]), fmaxf(st[2][mi][2], st[2][mi][3]));
      float t67 = fmaxf(fmaxf(st[3][mi][0], st[3][mi][1]), fmaxf(st[3][mi][2], st[3][mi][3]));
      float tm = fmaxf(fmaxf(t01, t23), fmaxf(t45, t67));
      tm = fmaxf(tm, __shfl_xor(tm, 16));
      tm = fmaxf(tm, __shfl_xor(tm, 32));
      float mn = fmaxf(mrow[mi], tm);
      float alpha = exp2f(mrow[mi] - mn);      // tile 0: exp2(-inf)=0
      mrow[mi] = mn;
      float ps = 0.f;
#pragma unroll
      for (int ni = 0; ni < 4; ni++) {
        float p0 = exp2f(st[ni][mi][0] - mn);
        float p1 = exp2f(st[ni][mi][1] - mn);
        float p2 = exp2f(st[ni][mi][2] - mn);
        float p3 = exp2f(st[ni][mi][3] - mn);
        ps += (p0 + p1) + (p2 + p3);
        uint2 w;
        w.x = cvt_pk_bf16(p0, p1);
        w.y = cvt_pk_bf16(p2, p3);
        *(uint2*)&myP[(mi * 16 + c) * 72 + ni * 16 + g * 4] = w;
      }
      lrow[mi] = lrow[mi] * alpha + ps;
      // redistribute alpha to O layout: lane needs alphas of q = g*4+r
      float ar[4];
#pragma unroll
      for (int r = 0; r < 4; r++) ar[r] = __shfl(alpha, 20 * g + r);
#pragma unroll
      for (int di = 0; di < 4; di++)
#pragma unroll
        for (int r = 0; r < 4; r++) oacc[mi][di][r] *= ar[r];
    }
    // ---- O += P V  (per-wave P: lgkmcnt orders write->read, no barrier) ----
#pragma unroll
    for (int ks = 0; ks < 2; ks++) {
      s16x8 pa[2], vbf[4];
#pragma unroll
      for (int mi = 0; mi < 2; mi++)
        pa[mi] = *(const s16x8*)&myP[(mi * 16 + c) * 72 + ks * 32 + g * 8];
#pragma unroll
      for (int di = 0; di < 4; di++)
        vbf[di] = *(const s16x8*)&Vl[(di * 16 + c) * 72 + ks * 32 + g * 8];
#pragma unroll
      for (int mi = 0; mi < 2; mi++)
#pragma unroll
        for (int di = 0; di < 4; di++)
          oacc[mi][di] = __builtin_amdgcn_mfma_f32_16x16x32_bf16(pa[mi], vbf[di], oacc[mi][di], 0, 0, 0);
    }
    __syncthreads();   // all waves done with Kl/Vl before restage
  }
  // ---- epilogue ----
#pragma unroll
  for (int mi = 0; mi < 2; mi++) {
    float l = lrow[mi];
    l += __shfl_xor(l, 16);
    l += __shfl_xor(l, 32);
    float inv = 1.f / l;
    float ir[4];
#pragma unroll
    for (int r = 0; r < 4; r++) ir[r] = __shfl(inv, 20 * g + r);
#pragma unroll
    for (int r = 0; r < 4; r++) {
      int qrow = qbase + mi * 16 + g * 4 + r;
#pragma unroll
      for (int di = 0; di < 4; di++) {
        int dc = di * 16 + c;
        aout[((size_t)(b * 4096 + qrow)) * 512 + h * 64 + dc] = (short)f2bf(oacc[mi][di][r] * ir[r]);
      }
    }
  }
}

// ---- kernel 3: proj GEMM ----
__global__ __launch_bounds__(256) void proj_gemm(
    const short* __restrict__ wp, const short* __restrict__ aout,
    const float* __restrict__ proj_b, float* __restrict__ out) {
  __shared__ short Al[128 * 40];
  __shared__ short Bl[128 * 40];
  const int b = blockIdx.z;
  const int m0 = blockIdx.y * 128, n0 = blockIdx.x * 128;
  const int t = threadIdx.x, lane = t & 63, wid = t >> 6;
  const int wr = wid >> 1, wc = wid & 1;
  const int srow = t >> 1, scol = (t & 1) * 16;
  const short* gA = wp + (size_t)(m0 + srow) * 512 + scol;
  const short* gB = aout + ((size_t)(b * 4096 + n0 + srow)) * 512 + scol;
  short* lA = &Al[srow * 40 + scol];
  short* lB = &Bl[srow * 40 + scol];
  f32x4 acc[4][4] = {};
  for (int ks = 0; ks < 16; ks++) {
    *(s16x8*)lA       = *(const s16x8*)(gA + ks * 32);
    *(s16x8*)(lA + 8) = *(const s16x8*)(gA + ks * 32 + 8);
    *(s16x8*)lB       = *(const s16x8*)(gB + ks * 32);
    *(s16x8*)(lB + 8) = *(const s16x8*)(gB + ks * 32 + 8);
    __syncthreads();
    s16x8 af[4], bf[4];
#pragma unroll
    for (int i = 0; i < 4; i++) {
      af[i] = *(const s16x8*)&Al[(wr * 64 + i * 16 + (lane & 15)) * 40 + ((lane >> 4) << 3)];
      bf[i] = *(const s16x8*)&Bl[(wc * 64 + i * 16 + (lane & 15)) * 40 + ((lane >> 4) << 3)];
    }
#pragma unroll
    for (int i = 0; i < 4; i++)
#pragma unroll
      for (int j = 0; j < 4; j++)
        acc[i][j] = __builtin_amdgcn_mfma_f32_16x16x32_bf16(af[i], bf[j], acc[i][j], 0, 0, 0);
    __syncthreads();
  }
#pragma unroll
  for (int i = 0; i < 4; i++)
#pragma unroll
    for (int r = 0; r < 4; r++) {
      int orow = m0 + wr * 64 + i * 16 + ((lane >> 4) << 2) + r;
      float bias = proj_b[orow];
#pragma unroll
      for (int j = 0; j < 4; j++) {
        int ncol = n0 + wc * 64 + j * 16 + (lane & 15);
        out[((size_t)(b * 512 + orow)) * 4096 + ncol] = acc[i][j][r] + bias;
      }
    }
}

extern "C" void kernel_launch(void* const* d_in, const int* in_sizes, int n_in,
                              void* d_out, int out_size, void* d_ws, size_t ws_size,
                              hipStream_t stream) {
  const float* x      = (const float*)d_in[0];
  const float* qkv_w  = (const float*)d_in[1];
  const float* qkv_b  = (const float*)d_in[2];
  const float* proj_w = (const float*)d_in[3];
  const float* proj_b = (const float*)d_in[4];
  float* out = (float*)d_out;
  char* ws = (char*)d_ws;
  short* wq = (short*)(ws);
  short* wp = (short*)(ws + 1572864);
  short* xt = (short*)(ws + 2097152);
  short* qk = (short*)(ws + 10485760);
  short* vb = (short*)(ws + 27262976);
  short* ao = (short*)(ws + 35651584);

  prep_weights  <<<1024, 256, 0, stream>>>(qkv_w, proj_w, wq, wp);
  prep_transpose<<<dim3(64, 8, 2), 256, 0, stream>>>(x, xt);
  qkv_gemm      <<<dim3(32, 12, 2), 256, 0, stream>>>(wq, xt, qkv_b, qk, vb);
  flash_attn    <<<dim3(32, 16), 256, 0, stream>>>(qk, vb, ao);
  proj_gemm     <<<dim3(32, 4, 2), 256, 0, stream>>>(wp, ao, proj_b, out);
}

// Round 5
// 253.838 us; speedup vs baseline: 1.6289x; 1.1371x over previous
//
#include <hip/hip_runtime.h>

// ---------------------------------------------------------------------------
// SelfAttention: x[2,512,64,64] f32 -> qkv(1x1conv) -> 8-head attn (n=4096,d=64)
// -> proj -> out [2,512,4096] f32.
// R4: 289us total; flash 188us (MfmaUtil 15.6, VALU 63, Occ 18.9 grid-capped).
// R5 flash rewrite: swapped PV (O^T = mfma(V,P): alpha/l/inv all in-lane at
// q=lane&15, no redistribution shuffles), T13 defer-max (THR=8 log2),
// 8 waves x 16 q-rows / 512-thread blocks -> 16 waves/CU (~50% occ).
// ---------------------------------------------------------------------------

typedef __attribute__((ext_vector_type(8))) short s16x8;   // 8 bf16 (4 VGPR)
typedef __attribute__((ext_vector_type(4))) float f32x4;   // mfma C/D
typedef __attribute__((ext_vector_type(4))) unsigned short u16x4;

__device__ __forceinline__ unsigned short f2bf(float f) {
  unsigned u = __builtin_bit_cast(unsigned, f);
  u += 0x7fffu + ((u >> 16) & 1u);           // round-to-nearest-even
  return (unsigned short)(u >> 16);
}

__device__ __forceinline__ unsigned cvt_pk_bf16(float lo, float hi) {
  unsigned r;
  asm("v_cvt_pk_bf16_f32 %0, %1, %2" : "=v"(r) : "v"(lo), "v"(hi));
  return r;  // low16 = bf16(lo), high16 = bf16(hi)
}

// ---- kernel 0a: convert qkv_w (1536x512) and proj_w (512x512) f32->bf16 ----
__global__ __launch_bounds__(256) void prep_weights(
    const float* __restrict__ qkv_w, const float* __restrict__ proj_w,
    short* __restrict__ wq, short* __restrict__ wp) {
  int t = blockIdx.x * 256 + threadIdx.x;
  const int NQ = 1536 * 512 / 4;
  if (t < NQ) {
    float4 v = ((const float4*)qkv_w)[t];
    u16x4 o; o[0] = f2bf(v.x); o[1] = f2bf(v.y); o[2] = f2bf(v.z); o[3] = f2bf(v.w);
    ((u16x4*)wq)[t] = o;
  } else {
    int t2 = t - NQ;
    float4 v = ((const float4*)proj_w)[t2];
    u16x4 o; o[0] = f2bf(v.x); o[1] = f2bf(v.y); o[2] = f2bf(v.z); o[3] = f2bf(v.w);
    ((u16x4*)wp)[t2] = o;
  }
}

// ---- kernel 0b: x [b][c=512][n=4096] f32 -> Xt [b][n][c] bf16 ----
__global__ __launch_bounds__(256) void prep_transpose(
    const float* __restrict__ x, short* __restrict__ xt) {
  __shared__ short TL[64 * 72];
  const int b = blockIdx.z, c0 = blockIdx.y * 64, n0 = blockIdx.x * 64;
  const int t = threadIdx.x;
  const int cr = t >> 4, n4 = (t & 15) * 4;
#pragma unroll
  for (int i = 0; i < 4; i++) {
    int c = cr + i * 16;
    float4 v = *(const float4*)(x + ((size_t)(b * 512 + c0 + c)) * 4096 + n0 + n4);
    TL[(n4 + 0) * 72 + c] = (short)f2bf(v.x);
    TL[(n4 + 1) * 72 + c] = (short)f2bf(v.y);
    TL[(n4 + 2) * 72 + c] = (short)f2bf(v.z);
    TL[(n4 + 3) * 72 + c] = (short)f2bf(v.w);
  }
  __syncthreads();
  const int n = t >> 2;
#pragma unroll
  for (int s2 = 0; s2 < 2; s2++) {
    int s = (t & 3) * 2 + s2;
    s16x8 v = *(const s16x8*)&TL[n * 72 + s * 8];
    *(s16x8*)(xt + ((size_t)(b * 4096 + n0 + n)) * 512 + c0 + s * 8) = v;
  }
}

// ---- kernel 1: qkv GEMM. Q,K emitted [n][o] (swapped), V [o][n] (natural).
//      Q additionally pre-scaled by 0.125*log2(e) for the flash exp2 path.
__global__ __launch_bounds__(256) void qkv_gemm(
    const short* __restrict__ wq, const short* __restrict__ xt,
    const float* __restrict__ qkv_b,
    short* __restrict__ qkbuf,   // [b][n][1024]  (Q cols 0..511 scaled, K 512..1023)
    short* __restrict__ vbuf) {  // [b][512][4096]
  __shared__ short Al[128 * 40];
  __shared__ short Bl[128 * 40];
  const int b = blockIdx.z;
  const int m0 = blockIdx.y * 128, n0 = blockIdx.x * 128;
  const bool swapped = (blockIdx.y < 8);
  const int t = threadIdx.x, lane = t & 63, wid = t >> 6;
  const int wr = wid >> 1, wc = wid & 1;
  const int srow = t >> 1, scol = (t & 1) * 16;
  const short* gA = wq + (size_t)(m0 + srow) * 512 + scol;
  const short* gB = xt + ((size_t)(b * 4096 + n0 + srow)) * 512 + scol;
  short* lA = &Al[srow * 40 + scol];
  short* lB = &Bl[srow * 40 + scol];
  const short* As = swapped ? Bl : Al;
  const short* Bs = swapped ? Al : Bl;
  f32x4 acc[4][4] = {};
  for (int ks = 0; ks < 16; ks++) {
    *(s16x8*)lA       = *(const s16x8*)(gA + ks * 32);
    *(s16x8*)(lA + 8) = *(const s16x8*)(gA + ks * 32 + 8);
    *(s16x8*)lB       = *(const s16x8*)(gB + ks * 32);
    *(s16x8*)(lB + 8) = *(const s16x8*)(gB + ks * 32 + 8);
    __syncthreads();
    s16x8 af[4], bf[4];
#pragma unroll
    for (int i = 0; i < 4; i++) {
      af[i] = *(const s16x8*)&As[(wr * 64 + i * 16 + (lane & 15)) * 40 + ((lane >> 4) << 3)];
      bf[i] = *(const s16x8*)&Bs[(wc * 64 + i * 16 + (lane & 15)) * 40 + ((lane >> 4) << 3)];
    }
#pragma unroll
    for (int i = 0; i < 4; i++)
#pragma unroll
      for (int j = 0; j < 4; j++)
        acc[i][j] = __builtin_amdgcn_mfma_f32_16x16x32_bf16(af[i], bf[j], acc[i][j], 0, 0, 0);
    __syncthreads();
  }
  if (!swapped) {                             // V region
#pragma unroll
    for (int i = 0; i < 4; i++)
#pragma unroll
      for (int r = 0; r < 4; r++) {
        int orow = m0 + wr * 64 + i * 16 + ((lane >> 4) << 2) + r;
        float bias = qkv_b[orow];
#pragma unroll
        for (int j = 0; j < 4; j++) {
          int ncol = n0 + wc * 64 + j * 16 + (lane & 15);
          vbuf[((size_t)(b * 512 + orow - 1024)) * 4096 + ncol] = (short)f2bf(acc[i][j][r] + bias);
        }
      }
  } else {                                    // Q/K region: D^T -> [n][o]
    const float qs = (m0 < 512) ? 0.18033688f : 1.0f;   // 0.125 * log2(e) for Q
#pragma unroll
    for (int j = 0; j < 4; j++) {
      int ocol = m0 + wc * 64 + j * 16 + (lane & 15);
      float bias = qkv_b[ocol];
#pragma unroll
      for (int i = 0; i < 4; i++)
#pragma unroll
        for (int r = 0; r < 4; r++) {
          int nrow = n0 + wr * 64 + i * 16 + ((lane >> 4) << 2) + r;
          qkbuf[((size_t)(b * 4096 + nrow)) * 1024 + ocol] = (short)f2bf((acc[i][j][r] + bias) * qs);
        }
    }
  }
}

// ---- kernel 2: flash attention v2 ----
// Block: one (b,h), 128 q-rows, 8 waves x 16 q-rows, 512 threads. KV tiles 64.
// S^T = mfma(K,Q): lane holds S[q=lane&15][k=ni*16+g*4+r]. Softmax in-lane.
// O^T = mfma(V,P): O[d=di*16+g*4+r][q=lane&15] -> alpha/l/inv in-lane.
// T13 defer-max: skip rescale while tile-max <= m+8 (log2 units).
__global__ __launch_bounds__(512) void flash_attn(
    const short* __restrict__ qkbuf, const short* __restrict__ vbuf,
    short* __restrict__ aout) {                // [b][n][512] bf16
  __shared__ short Kl[64 * 72];                // [kpos][d]
  __shared__ short Vl[64 * 72];                // [d][kpos]
  __shared__ short Pl[8 * 16 * 72];            // per-wave [q][kpos]
  const int t = threadIdx.x, lane = t & 63, wid = t >> 6;
  const int g = lane >> 4, c = lane & 15;
  const int bh = blockIdx.y, b = bh >> 3, h = bh & 7;
  const int qrow = blockIdx.x * 128 + wid * 16 + c;   // this lane's q row

  s16x8 qf[2];                                 // Q pre-scaled by 0.125*log2e
#pragma unroll
  for (int kd = 0; kd < 2; kd++)
    qf[kd] = *(const s16x8*)(qkbuf + ((size_t)(b * 4096 + qrow)) * 1024
                             + h * 64 + kd * 32 + g * 8);

  f32x4 oacc[4] = {};                          // O^T[d=di*16+g*4+r][q=c]
  float m = -__builtin_inff();
  float l = 0.f;                               // per-lane partial (16 k each)

  const int srow = t >> 3, sseg = (t & 7) * 8; // 8 shorts K + 8 shorts V per thread
  const short* gK = qkbuf + ((size_t)(b * 4096 + srow)) * 1024 + 512 + h * 64 + sseg;
  const short* gV = vbuf + ((size_t)(b * 512 + h * 64 + srow)) * 4096 + sseg;
  short* lK = &Kl[srow * 72 + sseg];
  short* lV = &Vl[srow * 72 + sseg];
  short* myP = &Pl[wid * 16 * 72];

  s16x8 rK = *(const s16x8*)gK;
  s16x8 rV = *(const s16x8*)gV;

  for (int kt = 0; kt < 64; kt++) {
    *(s16x8*)lK = rK;
    *(s16x8*)lV = rV;
    __syncthreads();
    if (kt < 63) {                             // prefetch next tile under compute
      rK = *(const s16x8*)(gK + (size_t)(kt + 1) * 64 * 1024);
      rV = *(const s16x8*)(gV + (kt + 1) * 64);
    }
    // ---- S^T = K Q^T ----
    s16x8 kf[4][2];
#pragma unroll
    for (int ni = 0; ni < 4; ni++)
#pragma unroll
      for (int kd = 0; kd < 2; kd++)
        kf[ni][kd] = *(const s16x8*)&Kl[(ni * 16 + c) * 72 + kd * 32 + g * 8];
    f32x4 st[4] = {};
#pragma unroll
    for (int ni = 0; ni < 4; ni++) {
      st[ni] = __builtin_amdgcn_mfma_f32_16x16x32_bf16(kf[ni][0], qf[0], st[ni], 0, 0, 0);
      st[ni] = __builtin_amdgcn_mfma_f32_16x16x32_bf16(kf[ni][1], qf[1], st[ni], 0, 0, 0);
    }
    // ---- softmax (in-lane; q = c) ----
    float t01 = fmaxf(fmaxf(st[0][0], st[0][1]), fmaxf(st[0][2], st[0][3]));
    float t23 = fmaxf(fmaxf(st[1][0], st[1][1]), fmaxf(st[1][2], st[1][3]));
    float t45 = fmaxf(fmaxf(st[2][0], st[2][1]), fmaxf(st[2][2], st[2][3]));
    float t67 = fmaxf(fmaxf(st[3][0], st[3][1]), fmaxf(st[3][2], st[3][3]));
    float tm = fmaxf(fmaxf(t01, t23), fmaxf(t45, t67));
    tm = fmaxf(tm, __shfl_xor(tm, 16));
    tm = fmaxf(tm, __shfl_xor(tm, 32));        // full-row max for q=c
    if (!__all(tm <= m + 8.f)) {               // T13: rescale only when needed
      float mn = fmaxf(m, tm);
      float alpha = exp2f(m - mn);             // tile 0: exp2(-inf)=0
      m = mn;
      l *= alpha;
#pragma unroll
      for (int di = 0; di < 4; di++)
#pragma unroll
        for (int r = 0; r < 4; r++) oacc[di][r] *= alpha;
    }
    float ps = 0.f;
#pragma unroll
    for (int ni = 0; ni < 4; ni++) {
      float p0 = exp2f(st[ni][0] - m);
      float p1 = exp2f(st[ni][1] - m);
      float p2 = exp2f(st[ni][2] - m);
      float p3 = exp2f(st[ni][3] - m);
      ps += (p0 + p1) + (p2 + p3);
      uint2 w;
      w.x = cvt_pk_bf16(p0, p1);
      w.y = cvt_pk_bf16(p2, p3);
      *(uint2*)&myP[c * 72 + ni * 16 + g * 4] = w;   // P[q=c][k]
    }
    l += ps;
    // ---- O^T += V^T P^T  (operand-swapped PV; per-wave P, lgkm-ordered) ----
#pragma unroll
    for (int ks = 0; ks < 2; ks++) {
      s16x8 pa = *(const s16x8*)&myP[c * 72 + ks * 32 + g * 8];
      s16x8 vbf[4];
#pragma unroll
      for (int di = 0; di < 4; di++)
        vbf[di] = *(const s16x8*)&Vl[(di * 16 + c) * 72 + ks * 32 + g * 8];
#pragma unroll
      for (int di = 0; di < 4; di++)
        oacc[di] = __builtin_amdgcn_mfma_f32_16x16x32_bf16(vbf[di], pa, oacc[di], 0, 0, 0);
    }
    __syncthreads();   // all waves done with Kl/Vl before restage
  }
  // ---- epilogue: all state in-lane at q=c ----
  float lf = l;
  lf += __shfl_xor(lf, 16);
  lf += __shfl_xor(lf, 32);
  float inv = 1.f / lf;
#pragma unroll
  for (int di = 0; di < 4; di++)
#pragma unroll
    for (int r = 0; r < 4; r++) {
      int d = di * 16 + g * 4 + r;
      aout[((size_t)(b * 4096 + qrow)) * 512 + h * 64 + d] = (short)f2bf(oacc[di][r] * inv);
    }
}

// ---- kernel 3: proj GEMM ----
__global__ __launch_bounds__(256) void proj_gemm(
    const short* __restrict__ wp, const short* __restrict__ aout,
    const float* __restrict__ proj_b, float* __restrict__ out) {
  __shared__ short Al[128 * 40];
  __shared__ short Bl[128 * 40];
  const int b = blockIdx.z;
  const int m0 = blockIdx.y * 128, n0 = blockIdx.x * 128;
  const int t = threadIdx.x, lane = t & 63, wid = t >> 6;
  const int wr = wid >> 1, wc = wid & 1;
  const int srow = t >> 1, scol = (t & 1) * 16;
  const short* gA = wp + (size_t)(m0 + srow) * 512 + scol;
  const short* gB = aout + ((size_t)(b * 4096 + n0 + srow)) * 512 + scol;
  short* lA = &Al[srow * 40 + scol];
  short* lB = &Bl[srow * 40 + scol];
  f32x4 acc[4][4] = {};
  for (int ks = 0; ks < 16; ks++) {
    *(s16x8*)lA       = *(const s16x8*)(gA + ks * 32);
    *(s16x8*)(lA + 8) = *(const s16x8*)(gA + ks * 32 + 8);
    *(s16x8*)lB       = *(const s16x8*)(gB + ks * 32);
    *(s16x8*)(lB + 8) = *(const s16x8*)(gB + ks * 32 + 8);
    __syncthreads();
    s16x8 af[4], bf[4];
#pragma unroll
    for (int i = 0; i < 4; i++) {
      af[i] = *(const s16x8*)&Al[(wr * 64 + i * 16 + (lane & 15)) * 40 + ((lane >> 4) << 3)];
      bf[i] = *(const s16x8*)&Bl[(wc * 64 + i * 16 + (lane & 15)) * 40 + ((lane >> 4) << 3)];
    }
#pragma unroll
    for (int i = 0; i < 4; i++)
#pragma unroll
      for (int j = 0; j < 4; j++)
        acc[i][j] = __builtin_amdgcn_mfma_f32_16x16x32_bf16(af[i], bf[j], acc[i][j], 0, 0, 0);
    __syncthreads();
  }
#pragma unroll
  for (int i = 0; i < 4; i++)
#pragma unroll
    for (int r = 0; r < 4; r++) {
      int orow = m0 + wr * 64 + i * 16 + ((lane >> 4) << 2) + r;
      float bias = proj_b[orow];
#pragma unroll
      for (int j = 0; j < 4; j++) {
        int ncol = n0 + wc * 64 + j * 16 + (lane & 15);
        out[((size_t)(b * 512 + orow)) * 4096 + ncol] = acc[i][j][r] + bias;
      }
    }
}

extern "C" void kernel_launch(void* const* d_in, const int* in_sizes, int n_in,
                              void* d_out, int out_size, void* d_ws, size_t ws_size,
                              hipStream_t stream) {
  const float* x      = (const float*)d_in[0];
  const float* qkv_w  = (const float*)d_in[1];
  const float* qkv_b  = (const float*)d_in[2];
  const float* proj_w = (const float*)d_in[3];
  const float* proj_b = (const float*)d_in[4];
  float* out = (float*)d_out;
  char* ws = (char*)d_ws;
  short* wq = (short*)(ws);
  short* wp = (short*)(ws + 1572864);
  short* xt = (short*)(ws + 2097152);
  short* qk = (short*)(ws + 10485760);
  short* vb = (short*)(ws + 27262976);
  short* ao = (short*)(ws + 35651584);

  prep_weights  <<<1024, 256, 0, stream>>>(qkv_w, proj_w, wq, wp);
  prep_transpose<<<dim3(64, 8, 2), 256, 0, stream>>>(x, xt);
  qkv_gemm      <<<dim3(32, 12, 2), 256, 0, stream>>>(wq, xt, qkv_b, qk, vb);
  flash_attn    <<<dim3(32, 16), 512, 0, stream>>>(qk, vb, ao);
  proj_gemm     <<<dim3(32, 4, 2), 256, 0, stream>>>(wp, ao, proj_b, out);
}